// Round 8
// baseline (1183.396 us; speedup 1.0000x reference)
//
#include <hip/hip_runtime.h>
#include <math.h>

#define NN    10000
#define SSS   4
#define LL    8
#define HH    128
#define GG    384
#define NSEQ  40000
#define SUBN  100
#define ORIGF 64
#define MA    16
#define TA    384

typedef unsigned short u16;
typedef short bf16x8 __attribute__((ext_vector_type(8)));
typedef float f32x4 __attribute__((ext_vector_type(4)));

// ---- LDS layout (bytes) ----
#define XB_STR   136            // u16 cols per row (128 + 8 pad)
#define XB_OFF   0              // u16[128][136]  y_walk, row = t*16+m
#define HB_OFF   34816          // u16[16][136]   bf16 h mirror
#define HB_STR   136
#define SG_OFF   39168          // f32[16][385]   gate staging
#define SG_STR   385
#define SGN_OFF  63808          // f32[16][132]   gi_n staging
#define SGN_STR  132
#define SH_OFF   72256          // f32[16][128]   fp32 master h
#define SWF_OFF  80448          // int[16][8]
#define SUF_OFF  80960          // int[16][8]
#define SCNT_OFF 81472          // int[16]
#define SANY_OFF 81536          // int
#define LDS_TOTAL 81552

// ws layout: ws[0..3] accum; byte 64: bf16 weights (whhw|whh|wih)
#define WB_BYTE_OFF 64
#define W_HHW_N 49152
#define W_HH_N  49152
#define W_IH_N  98304
#define W_TOTAL (W_HHW_N + W_HH_N + W_IH_N)

__device__ __forceinline__ u16 f2bf(float f) {
  unsigned u = __float_as_uint(f);
  u += 0x7fffu + ((u >> 16) & 1u);   // RNE
  return (u16)(u >> 16);
}
__device__ __forceinline__ bf16x8 pack8(float4 v0, float4 v1) {
  bf16x8 r;
  r[0] = (short)f2bf(v0.x); r[1] = (short)f2bf(v0.y);
  r[2] = (short)f2bf(v0.z); r[3] = (short)f2bf(v0.w);
  r[4] = (short)f2bf(v1.x); r[5] = (short)f2bf(v1.y);
  r[6] = (short)f2bf(v1.z); r[7] = (short)f2bf(v1.w);
  return r;
}
__device__ __forceinline__ float sigmoidf_(float x) { return 1.f / (1.f + __expf(-x)); }
__device__ __forceinline__ float softplusf_(float x) {
  return fmaxf(x, 0.f) + log1pf(__expf(-fabsf(x)));
}

__global__ void k_zero(float* ws) {
  if (threadIdx.x < 4) ws[threadIdx.x] = 0.f;
}

__global__ void k_prep(const float* __restrict__ whhw, const float* __restrict__ whh,
                       const float* __restrict__ wih, float* __restrict__ ws) {
  const int i = blockIdx.x * 256 + threadIdx.x;
  u16* wb = (u16*)((char*)ws + WB_BYTE_OFF);
  if (i < W_HHW_N)                wb[i] = f2bf(whhw[i]);
  else if (i < W_HHW_N + W_HH_N)  wb[i] = f2bf(whh[i - W_HHW_N]);
  else                            wb[i] = f2bf(wih[i - W_HHW_N - W_HH_N]);
}

__global__ __launch_bounds__(TA, 2) void k_rum(
    const float* __restrict__ hfeat, const float* __restrict__ y0,
    const float* __restrict__ WihW,  const float* __restrict__ bihW,
    const float* __restrict__ bhhW,
    const float* __restrict__ bih,   const float* __restrict__ bhh,
    const float* __restrict__ W_ss,  const float* __restrict__ b_ss,
    const int* __restrict__ walks,   const int* __restrict__ idxs,
    float* __restrict__ out, float* __restrict__ ws)
{
  extern __shared__ char sm[];
  u16*   xb  = (u16*)(sm + XB_OFF);
  u16*   hb  = (u16*)(sm + HB_OFF);
  float* sg  = (float*)(sm + SG_OFF);
  float* sgn = (float*)(sm + SGN_OFF);
  float* sh  = (float*)(sm + SH_OFF);
  int*   swf = (int*)(sm + SWF_OFF);
  int*   suf = (int*)(sm + SUF_OFF);
  int*   scnt= (int*)(sm + SCNT_OFF);
  int*   sany= (int*)(sm + SANY_OFF);

  const u16* wb     = (const u16*)((const char*)ws + WB_BYTE_OFF);
  const u16* whhw_b = wb;
  const u16* whh_b  = wb + W_HHW_N;
  const u16* wih_b  = wb + W_HHW_N + W_HH_N;

  const int tid = threadIdx.x;
  const int lane = tid & 63, c = lane & 15, qd = lane >> 4;
  const int wv = tid >> 6, col0 = wv * 64;
  const int q0 = blockIdx.x * MA;

  // ---- phase 0 ----
  if (tid < MA) {
    const int m = tid;
    scnt[m] = 0;
    const int q = q0 + m;
    int w[LL];
    #pragma unroll
    for (int l = 0; l < LL; ++l) w[l] = walks[q * LL + l];
    #pragma unroll
    for (int l = 0; l < LL; ++l) {
      int u = l;
      #pragma unroll
      for (int l2 = LL - 1; l2 >= 0; --l2) if (w[l2] == w[l]) u = l2;
      swf[m * LL + (LL - 1 - l)] = w[l];
      suf[m * LL + (LL - 1 - l)] = u;
    }
  }
  if (tid == 0) *sany = 0;
  for (int idx = tid; idx < MA * HH; idx += TA) {
    sh[idx] = 0.f;
    hb[(idx >> 7) * HB_STR + (idx & 127)] = 0;
  }
  __syncthreads();

  for (int p = tid; p < MA * SUBN; p += TA) {
    const int m = p / SUBN, i = p % SUBN;
    if (idxs[i] == (q0 + m) % NN) { atomicAdd(&scnt[m], 1); *sany = 1; }
  }

  // ---- phase A: walk GRU; y_walk -> xb ----
  {
    bf16x8 BA[4][4];
    #pragma unroll
    for (int n = 0; n < 4; ++n)
      #pragma unroll
      for (int k = 0; k < 4; ++k)
        BA[n][k] = *(const bf16x8*)(whhw_b + (col0 + n * 16 + c) * HH + k * 32 + qd * 8);

    #pragma unroll 1
    for (int t = 0; t < LL; ++t) {
      bf16x8 a[4];
      #pragma unroll
      for (int k = 0; k < 4; ++k)
        a[k] = *(const bf16x8*)(hb + c * HB_STR + k * 32 + qd * 8);
      #pragma unroll
      for (int n = 0; n < 4; ++n) {
        f32x4 d = {0.f, 0.f, 0.f, 0.f};
        #pragma unroll
        for (int k = 0; k < 4; ++k)
          d = __builtin_amdgcn_mfma_f32_16x16x32_bf16(a[k], BA[n][k], d, 0, 0, 0);
        #pragma unroll
        for (int reg = 0; reg < 4; ++reg)
          sg[(qd * 4 + reg) * SG_STR + col0 + n * 16 + c] = d[reg];
      }
      __syncthreads();
      for (int idx = tid; idx < MA * HH; idx += TA) {
        const int m = idx >> 7, i = idx & 127;
        const int u = suf[m * LL + t];
        const float gir = WihW[i * LL + u] + bihW[i];
        const float giz = WihW[(HH + i) * LL + u] + bihW[HH + i];
        const float gin = WihW[(2 * HH + i) * LL + u] + bihW[2 * HH + i];
        const float r = sigmoidf_(gir + sg[m * SG_STR + i] + bhhW[i]);
        const float z = sigmoidf_(giz + sg[m * SG_STR + HH + i] + bhhW[HH + i]);
        const float n = tanhf(gin + r * (sg[m * SG_STR + 2 * HH + i] + bhhW[2 * HH + i]));
        const float hn = (1.f - z) * n + z * sh[m * HH + i];
        sh[m * HH + i] = hn;
        const u16 hv = f2bf(hn);
        hb[m * HB_STR + i] = hv;
        xb[(t * 16 + m) * XB_STR + i] = hv;
      }
      __syncthreads();
    }
  }

  float pAcc = 0.f, pBcc = 0.f, pScc = 0.f;

  // ---- phases B+C, 4 passes of 2 timesteps ----
  #pragma unroll 1
  for (int pass = 0; pass < 4; ++pass) {
    f32x4 gi[2][4];
    #pragma unroll
    for (int rt = 0; rt < 2; ++rt)
      #pragma unroll
      for (int n = 0; n < 4; ++n)
        gi[rt][n] = (f32x4){0.f, 0.f, 0.f, 0.f};

    // stage A-fragments: hfeat (global f32 -> bf16) and y_walk (LDS)
    bf16x8 ah[2][4], ay[2][4];
    #pragma unroll
    for (int rt = 0; rt < 2; ++rt) {
      const int t = pass * 2 + rt;
      const int node = swf[c * LL + t];
      #pragma unroll
      for (int kt = 0; kt < 4; ++kt) {
        const float* hp = hfeat + (size_t)node * HH + kt * 32 + qd * 8;
        ah[rt][kt] = pack8(*(const float4*)hp, *(const float4*)(hp + 4));
        ay[rt][kt] = *(const bf16x8*)(xb + (t * 16 + c) * XB_STR + kt * 32 + qd * 8);
      }
    }

    // phase B: gi += [hfeat|y_walk] @ Wih^T
    #pragma unroll
    for (int n = 0; n < 4; ++n) {
      bf16x8 bw[8];
      #pragma unroll
      for (int kt = 0; kt < 8; ++kt)
        bw[kt] = *(const bf16x8*)(wih_b + (col0 + n * 16 + c) * 256 + kt * 32 + qd * 8);
      #pragma unroll
      for (int rt = 0; rt < 2; ++rt) {
        #pragma unroll
        for (int kt = 0; kt < 4; ++kt)
          gi[rt][n] = __builtin_amdgcn_mfma_f32_16x16x32_bf16(ah[rt][kt], bw[kt], gi[rt][n], 0, 0, 0);
        #pragma unroll
        for (int kt = 0; kt < 4; ++kt)
          gi[rt][n] = __builtin_amdgcn_mfma_f32_16x16x32_bf16(ay[rt][kt], bw[4 + kt], gi[rt][n], 0, 0, 0);
      }
    }

    // phase C: recurrence for the 2 steps
    #pragma unroll
    for (int rt = 0; rt < 2; ++rt) {
      const int t = pass * 2 + rt;
      bf16x8 a[4];
      #pragma unroll
      for (int k = 0; k < 4; ++k)
        a[k] = *(const bf16x8*)(hb + c * HB_STR + k * 32 + qd * 8);
      #pragma unroll
      for (int n = 0; n < 4; ++n) {
        bf16x8 bc[4];
        #pragma unroll
        for (int k = 0; k < 4; ++k)
          bc[k] = *(const bf16x8*)(whh_b + (col0 + n * 16 + c) * HH + k * 32 + qd * 8);
        f32x4 d = {0.f, 0.f, 0.f, 0.f};
        #pragma unroll
        for (int k = 0; k < 4; ++k)
          d = __builtin_amdgcn_mfma_f32_16x16x32_bf16(a[k], bc[k], d, 0, 0, 0);
        if (wv < 4) {
          #pragma unroll
          for (int reg = 0; reg < 4; ++reg)
            sg[(qd * 4 + reg) * SG_STR + col0 + n * 16 + c] = d[reg] + gi[rt][n][reg];
        } else {
          #pragma unroll
          for (int reg = 0; reg < 4; ++reg) {
            const int row = qd * 4 + reg;
            sg[row * SG_STR + col0 + n * 16 + c] = d[reg];
            sgn[row * SGN_STR + (col0 - 2 * HH) + n * 16 + c] = gi[rt][n][reg];
          }
        }
      }
      __syncthreads();
      for (int idx = tid; idx < MA * HH; idx += TA) {
        const int m = idx >> 7, i = idx & 127;
        const float r = sigmoidf_(sg[m * SG_STR + i] + bih[i] + bhh[i]);
        const float z = sigmoidf_(sg[m * SG_STR + HH + i] + bih[HH + i] + bhh[HH + i]);
        const float n = tanhf(sgn[m * SGN_STR + i] + bih[2 * HH + i]
                              + r * (sg[m * SG_STR + 2 * HH + i] + bhh[2 * HH + i]));
        const float hn = (1.f - z) * n + z * sh[m * HH + i];
        sh[m * HH + i] = hn;
        hb[m * HB_STR + i] = f2bf(hn);
      }
      __syncthreads();

      if (t < LL - 1 && *sany) {
        for (int idx = tid; idx < MA * ORIGF; idx += TA) {
          const int m = idx >> 6, o = idx & 63;
          const int cnt = scnt[m];
          if (cnt > 0) {
            const float* wr = W_ss + o * HH;
            float acc = b_ss[o];
            #pragma unroll 1
            for (int kc = 0; kc < HH; kc += 8) {
              const float4 wa = *(const float4*)(wr + kc);
              const float4 wb4 = *(const float4*)(wr + kc + 4);
              const float4 xa = *(const float4*)(&sh[m * HH + kc]);
              const float4 xv = *(const float4*)(&sh[m * HH + kc + 4]);
              acc = fmaf(wa.x, xa.x, acc); acc = fmaf(wa.y, xa.y, acc);
              acc = fmaf(wa.z, xa.z, acc); acc = fmaf(wa.w, xa.w, acc);
              acc = fmaf(wb4.x, xv.x, acc); acc = fmaf(wb4.y, xv.y, acc);
              acc = fmaf(wb4.z, xv.z, acc); acc = fmaf(wb4.w, xv.w, acc);
            }
            const float fc = (float)cnt;
            const float yt = y0[(size_t)swf[m * LL + t + 1] * ORIGF + o];
            pAcc += fc * yt * softplusf_(-acc);
            pBcc += fc * (1.f - yt) * softplusf_(acc);
            pScc += fc * yt;
          }
        }
      }
    }
  }

  // ---- epilogue ----
  for (int idx = tid; idx < MA * HH; idx += TA)
    out[(size_t)(q0 + (idx >> 7)) * HH + (idx & 127)] = sh[idx];

  if (*sany) {
    float* red = sg;
    red[tid] = pAcc; red[TA + tid] = pBcc; red[2 * TA + tid] = pScc;
    __syncthreads();
    if (tid == 0) {
      float a = 0.f, b = 0.f, s = 0.f;
      for (int k = 0; k < TA; ++k) { a += red[k]; b += red[TA + k]; s += red[2 * TA + k]; }
      atomicAdd(&ws[1], a);
      atomicAdd(&ws[2], b);
      atomicAdd(&ws[3], s);
    }
  }
}

__global__ void k_final(const float* __restrict__ ws, float* __restrict__ out) {
  if (threadIdx.x == 0) {
    const float cnt = (float)(SSS * SUBN * (LL - 1) * ORIGF);  // 179200
    const float pos_w = cnt / ws[3];
    const float loss = (pos_w * ws[1] + ws[2]) / cnt;
    out[NSEQ * HH] = loss;
  }
}

extern "C" void kernel_launch(void* const* d_in, const int* in_sizes, int n_in,
                              void* d_out, int out_size, void* d_ws, size_t ws_size,
                              hipStream_t stream) {
  const float* hfeat = (const float*)d_in[0];
  const float* y0    = (const float*)d_in[1];
  const float* Wih_w = (const float*)d_in[2];
  const float* Whh_w = (const float*)d_in[3];
  const float* bih_w = (const float*)d_in[4];
  const float* bhh_w = (const float*)d_in[5];
  const float* Wih   = (const float*)d_in[6];
  const float* Whh   = (const float*)d_in[7];
  const float* bih   = (const float*)d_in[8];
  const float* bhh   = (const float*)d_in[9];
  const float* W_ss  = (const float*)d_in[10];
  const float* b_ss  = (const float*)d_in[11];
  const int* walks = (const int*)d_in[12];
  const int* idxs  = (const int*)d_in[13];
  float* out = (float*)d_out;
  float* ws = (float*)d_ws;

  (void)hipFuncSetAttribute((const void*)k_rum,
                            hipFuncAttributeMaxDynamicSharedMemorySize, LDS_TOTAL);

  k_zero<<<1, 64, 0, stream>>>(ws);
  k_prep<<<W_TOTAL / 256, 256, 0, stream>>>(Whh_w, Whh, Wih, ws);

  const int grid = NSEQ / MA;               // 2500, exact
  k_rum<<<grid, TA, LDS_TOTAL, stream>>>(hfeat, y0, Wih_w, bih_w, bhh_w,
                                         bih, bhh, W_ss, b_ss,
                                         walks, idxs, out, ws);

  k_final<<<1, 64, 0, stream>>>(ws, out);
}

// Round 9
// 621.153 us; speedup vs baseline: 1.9052x; 1.9052x over previous
//
#include <hip/hip_runtime.h>
#include <math.h>

#define NN    10000
#define SSS   4
#define LL    8
#define HH    128
#define NSEQ  40000
#define SUBN  100
#define ORIGF 64
#define MA    16
#define TA    512

typedef unsigned short u16;
typedef short bf16x8 __attribute__((ext_vector_type(8)));
typedef float f32x4 __attribute__((ext_vector_type(4)));

// ---- LDS layout (bytes) ----
#define WL_OFF    0        // f32[384*8]  staged Wih_w
#define BWRZ_OFF  12288    // f32[256]    bihW+bhhW (r,z)
#define BWIN_OFF  13312    // f32[128]    bihW n
#define BWHN_OFF  13824    // f32[128]    bhhW n
#define BMRZ_OFF  14336    // f32[256]    bih+bhh (r,z)
#define BMIN_OFF  15360    // f32[128]    bih n
#define BMHN_OFF  15872    // f32[128]    bhh n
#define SH_OFF    16384    // f32[16*128] fp32 master h
#define HB_OFF    24576    // u16[2][16*136] bf16 h, double-buffered
#define HBBUF     2176
#define HB_STR    136
#define XB_OFF    33280    // u16[128*136] y_walk (t*16+m rows)
#define XB_STR    136
#define SWF_OFF   68096    // int[16*8]
#define SUF_OFF   68608    // int[16*8]
#define SCNT_OFF  69120    // int[16]
#define SANY_OFF  69184    // int
#define LDS_TOTAL 69200

// ws: ws[0..3] accum; byte 64: bf16 weights (whhw | whh | wih)
#define WB_BYTE_OFF 64
#define W_HHW_N 49152
#define W_HH_N  49152
#define W_IH_N  98304
#define W_TOTAL (W_HHW_N + W_HH_N + W_IH_N)

__device__ __forceinline__ u16 f2bf(float f) {
  unsigned u = __float_as_uint(f);
  u += 0x7fffu + ((u >> 16) & 1u);   // RNE
  return (u16)(u >> 16);
}
__device__ __forceinline__ bf16x8 pack8(float4 v0, float4 v1) {
  bf16x8 r;
  r[0] = (short)f2bf(v0.x); r[1] = (short)f2bf(v0.y);
  r[2] = (short)f2bf(v0.z); r[3] = (short)f2bf(v0.w);
  r[4] = (short)f2bf(v1.x); r[5] = (short)f2bf(v1.y);
  r[6] = (short)f2bf(v1.z); r[7] = (short)f2bf(v1.w);
  return r;
}
__device__ __forceinline__ float sigmoidf_(float x) { return 1.f / (1.f + __expf(-x)); }
__device__ __forceinline__ float tanhf_(float x) {   // NaN-free fast tanh
  const float e = __expf(2.f * x);
  return 1.f - 2.f / (e + 1.f);
}
__device__ __forceinline__ float softplusf_(float x) {
  return fmaxf(x, 0.f) + log1pf(__expf(-fabsf(x)));
}

__global__ void k_zero(float* ws) {
  if (threadIdx.x < 4) ws[threadIdx.x] = 0.f;
}

__global__ void k_prep(const float* __restrict__ whhw, const float* __restrict__ whh,
                       const float* __restrict__ wih, float* __restrict__ ws) {
  const int i = blockIdx.x * 256 + threadIdx.x;
  u16* wb = (u16*)((char*)ws + WB_BYTE_OFF);
  if (i < W_HHW_N)                wb[i] = f2bf(whhw[i]);
  else if (i < W_HHW_N + W_HH_N)  wb[i] = f2bf(whh[i - W_HHW_N]);
  else                            wb[i] = f2bf(wih[i - W_HHW_N - W_HH_N]);
}

__global__ __launch_bounds__(TA, 2) void k_rum(
    const float* __restrict__ hfeat, const float* __restrict__ y0,
    const float* __restrict__ WihW,  const float* __restrict__ bihW,
    const float* __restrict__ bhhW,
    const float* __restrict__ bih,   const float* __restrict__ bhh,
    const float* __restrict__ W_ss,  const float* __restrict__ b_ss,
    const int* __restrict__ walks,   const int* __restrict__ idxs,
    float* __restrict__ out, float* __restrict__ ws)
{
  extern __shared__ char sm[];
  float* WL   = (float*)(sm + WL_OFF);
  float* bwrz = (float*)(sm + BWRZ_OFF);
  float* bwin = (float*)(sm + BWIN_OFF);
  float* bwhn = (float*)(sm + BWHN_OFF);
  float* bmrz = (float*)(sm + BMRZ_OFF);
  float* bmin = (float*)(sm + BMIN_OFF);
  float* bmhn = (float*)(sm + BMHN_OFF);
  float* sh   = (float*)(sm + SH_OFF);
  u16*   hb   = (u16*)(sm + HB_OFF);      // [2][HBBUF]
  u16*   xb   = (u16*)(sm + XB_OFF);
  int*   swf  = (int*)(sm + SWF_OFF);
  int*   suf  = (int*)(sm + SUF_OFF);
  int*   scnt = (int*)(sm + SCNT_OFF);
  int*   sany = (int*)(sm + SANY_OFF);

  const u16* wb     = (const u16*)((const char*)ws + WB_BYTE_OFF);
  const u16* whhw_b = wb;
  const u16* whh_b  = wb + W_HHW_N;
  const u16* wih_b  = wb + W_HHW_N + W_HH_N;

  const int tid = threadIdx.x;
  const int lane = tid & 63, c = lane & 15, qd = lane >> 4;
  const int wv = tid >> 6;                  // 0..7: owns gate-tiles {wv, 8+wv, 16+wv}
  const int i0 = wv * 16 + c;               // this lane's hidden index
  const int q0 = blockIdx.x * MA;

  // ---- phase 0: staging + walk preprocessing ----
  if (tid < MA) {
    const int m = tid;
    scnt[m] = 0;
    const int q = q0 + m;
    int w[LL];
    #pragma unroll
    for (int l = 0; l < LL; ++l) w[l] = walks[q * LL + l];
    #pragma unroll
    for (int l = 0; l < LL; ++l) {
      int u = l;
      #pragma unroll
      for (int l2 = LL - 1; l2 >= 0; --l2) if (w[l2] == w[l]) u = l2;
      swf[m * LL + (LL - 1 - l)] = w[l];
      suf[m * LL + (LL - 1 - l)] = u;
    }
  }
  if (tid == 0) *sany = 0;
  for (int idx = tid; idx < 3072; idx += TA) WL[idx] = WihW[idx];
  if (tid < 256) { bwrz[tid] = bihW[tid] + bhhW[tid]; bmrz[tid] = bih[tid] + bhh[tid]; }
  if (tid < 128) {
    bwin[tid] = bihW[256 + tid]; bwhn[tid] = bhhW[256 + tid];
    bmin[tid] = bih[256 + tid];  bmhn[tid] = bhh[256 + tid];
  }
  for (int idx = tid; idx < MA * HH; idx += TA) sh[idx] = 0.f;
  for (int idx = tid; idx < HBBUF; idx += TA) hb[idx] = 0;
  __syncthreads();

  for (int p = tid; p < MA * SUBN; p += TA) {
    const int m = p / SUBN, i = p % SUBN;
    if (idxs[i] == (q0 + m) % NN) { atomicAdd(&scnt[m], 1); *sany = 1; }
  }

  // ---- walk GRU: wave-local activation, 1 barrier/step ----
  {
    bf16x8 BA[3][4];
    #pragma unroll
    for (int tl = 0; tl < 3; ++tl) {
      const int row = (tl * 8 + wv) * 16 + c;
      #pragma unroll
      for (int k = 0; k < 4; ++k)
        BA[tl][k] = *(const bf16x8*)(whhw_b + row * HH + k * 32 + qd * 8);
    }
    #pragma unroll
    for (int t = 0; t < LL; ++t) {
      const u16* hbc = hb + (t & 1) * HBBUF;
      u16*       hbn = hb + ((t + 1) & 1) * HBBUF;
      bf16x8 a[4];
      #pragma unroll
      for (int k = 0; k < 4; ++k)
        a[k] = *(const bf16x8*)(hbc + c * HB_STR + k * 32 + qd * 8);
      f32x4 D[3];
      #pragma unroll
      for (int tl = 0; tl < 3; ++tl) {
        f32x4 d = {0.f, 0.f, 0.f, 0.f};
        #pragma unroll
        for (int k = 0; k < 4; ++k)
          d = __builtin_amdgcn_mfma_f32_16x16x32_bf16(a[k], BA[tl][k], d, 0, 0, 0);
        D[tl] = d;
      }
      #pragma unroll
      for (int reg = 0; reg < 4; ++reg) {
        const int m = qd * 4 + reg;
        const int u = suf[m * LL + t];
        const float r = sigmoidf_(WL[i0 * LL + u] + D[0][reg] + bwrz[i0]);
        const float z = sigmoidf_(WL[(HH + i0) * LL + u] + D[1][reg] + bwrz[HH + i0]);
        const float n = tanhf_(WL[(2 * HH + i0) * LL + u] + bwin[i0]
                               + r * (D[2][reg] + bwhn[i0]));
        const float hn = (1.f - z) * n + z * sh[m * HH + i0];
        sh[m * HH + i0] = hn;
        const u16 hv = f2bf(hn);
        hbn[m * HB_STR + i0] = hv;
        xb[(t * 16 + m) * XB_STR + i0] = hv;
      }
      __syncthreads();
    }
  }

  // ---- load main-phase weight fragments ----
  bf16x8 BW[3][8], BC[3][4];
  #pragma unroll
  for (int tl = 0; tl < 3; ++tl) {
    const int row = (tl * 8 + wv) * 16 + c;
    #pragma unroll
    for (int kk = 0; kk < 8; ++kk)
      BW[tl][kk] = *(const bf16x8*)(wih_b + row * 256 + kk * 32 + qd * 8);
    #pragma unroll
    for (int k = 0; k < 4; ++k)
      BC[tl][k] = *(const bf16x8*)(whh_b + row * HH + k * 32 + qd * 8);
  }

  // input-gate pre-activations for step t: computed one step ahead, registers only
  f32x4 gi[2][3];
  auto doB = [&](int t, f32x4* g) {
    bf16x8 ah[4], ay[4];
    const int node = swf[c * LL + t];
    #pragma unroll
    for (int k = 0; k < 4; ++k) {
      const float* hp = hfeat + (size_t)node * HH + k * 32 + qd * 8;
      ah[k] = pack8(*(const float4*)hp, *(const float4*)(hp + 4));
      ay[k] = *(const bf16x8*)(xb + (t * 16 + c) * XB_STR + k * 32 + qd * 8);
    }
    #pragma unroll
    for (int tl = 0; tl < 3; ++tl) {
      f32x4 d = {0.f, 0.f, 0.f, 0.f};
      #pragma unroll
      for (int k = 0; k < 4; ++k)
        d = __builtin_amdgcn_mfma_f32_16x16x32_bf16(ah[k], BW[tl][k], d, 0, 0, 0);
      #pragma unroll
      for (int k = 0; k < 4; ++k)
        d = __builtin_amdgcn_mfma_f32_16x16x32_bf16(ay[k], BW[tl][4 + k], d, 0, 0, 0);
      g[tl] = d;
    }
  };
  doB(0, gi[0]);

  float pAcc = 0.f, pBcc = 0.f, pScc = 0.f;

  // ---- main GRU: 1 barrier/step (+1 in the ~15% loss blocks) ----
  #pragma unroll
  for (int t = 0; t < LL; ++t) {
    const u16* hbc = hb + (t & 1) * HBBUF;
    u16*       hbn = hb + ((t + 1) & 1) * HBBUF;
    bf16x8 a[4];
    #pragma unroll
    for (int k = 0; k < 4; ++k)
      a[k] = *(const bf16x8*)(hbc + c * HB_STR + k * 32 + qd * 8);
    f32x4 D[3];
    #pragma unroll
    for (int tl = 0; tl < 3; ++tl) {
      f32x4 d = {0.f, 0.f, 0.f, 0.f};
      #pragma unroll
      for (int k = 0; k < 4; ++k)
        d = __builtin_amdgcn_mfma_f32_16x16x32_bf16(a[k], BC[tl][k], d, 0, 0, 0);
      D[tl] = d;
    }
    const f32x4* gp = gi[t & 1];
    #pragma unroll
    for (int reg = 0; reg < 4; ++reg) {
      const int m = qd * 4 + reg;
      const float r = sigmoidf_(D[0][reg] + gp[0][reg] + bmrz[i0]);
      const float z = sigmoidf_(D[1][reg] + gp[1][reg] + bmrz[HH + i0]);
      const float n = tanhf_(gp[2][reg] + bmin[i0] + r * (D[2][reg] + bmhn[i0]));
      const float hn = (1.f - z) * n + z * sh[m * HH + i0];
      sh[m * HH + i0] = hn;
      hbn[m * HB_STR + i0] = f2bf(hn);
    }

    if (t < LL - 1 && *sany) {          // block-uniform branch
      __syncthreads();                  // sh rows complete for cross-wave read
      for (int idx = tid; idx < MA * ORIGF; idx += TA) {
        const int m = idx >> 6, o = idx & 63;
        const int cnt = scnt[m];
        if (cnt > 0) {
          const float* wr = W_ss + o * HH;
          float acc = b_ss[o];
          #pragma unroll 1
          for (int kc = 0; kc < HH; kc += 8) {
            const float4 wa = *(const float4*)(wr + kc);
            const float4 wb4 = *(const float4*)(wr + kc + 4);
            const float4 xa = *(const float4*)(&sh[m * HH + kc]);
            const float4 xv = *(const float4*)(&sh[m * HH + kc + 4]);
            acc = fmaf(wa.x, xa.x, acc); acc = fmaf(wa.y, xa.y, acc);
            acc = fmaf(wa.z, xa.z, acc); acc = fmaf(wa.w, xa.w, acc);
            acc = fmaf(wb4.x, xv.x, acc); acc = fmaf(wb4.y, xv.y, acc);
            acc = fmaf(wb4.z, xv.z, acc); acc = fmaf(wb4.w, xv.w, acc);
          }
          const float fc = (float)cnt;
          const float yt = y0[(size_t)swf[m * LL + t + 1] * ORIGF + o];
          pAcc += fc * yt * softplusf_(-acc);
          pBcc += fc * (1.f - yt) * softplusf_(acc);
          pScc += fc * yt;
        }
      }
    }
    __syncthreads();
    if (t < LL - 1) doB(t + 1, gi[(t + 1) & 1]);
  }

  // ---- epilogue: hT + loss reduction ----
  for (int idx = tid; idx < MA * HH; idx += TA)
    out[(size_t)(q0 + (idx >> 7)) * HH + (idx & 127)] = sh[idx];

  if (*sany) {
    float* red = (float*)(sm + WL_OFF);   // WL dead after walk phase
    red[tid] = pAcc; red[TA + tid] = pBcc; red[2 * TA + tid] = pScc;
    __syncthreads();
    if (wv == 0) {
      float a = 0.f, b = 0.f, s = 0.f;
      for (int k2 = lane; k2 < TA; k2 += 64) {
        a += red[k2]; b += red[TA + k2]; s += red[2 * TA + k2];
      }
      #pragma unroll
      for (int off = 32; off > 0; off >>= 1) {
        a += __shfl_down(a, off); b += __shfl_down(b, off); s += __shfl_down(s, off);
      }
      if (lane == 0) {
        atomicAdd(&ws[1], a); atomicAdd(&ws[2], b); atomicAdd(&ws[3], s);
      }
    }
  }
}

__global__ void k_final(const float* __restrict__ ws, float* __restrict__ out) {
  if (threadIdx.x == 0) {
    const float cnt = (float)(SSS * SUBN * (LL - 1) * ORIGF);  // 179200
    const float pos_w = cnt / ws[3];
    const float loss = (pos_w * ws[1] + ws[2]) / cnt;
    out[NSEQ * HH] = loss;
  }
}

extern "C" void kernel_launch(void* const* d_in, const int* in_sizes, int n_in,
                              void* d_out, int out_size, void* d_ws, size_t ws_size,
                              hipStream_t stream) {
  const float* hfeat = (const float*)d_in[0];
  const float* y0    = (const float*)d_in[1];
  const float* Wih_w = (const float*)d_in[2];
  const float* Whh_w = (const float*)d_in[3];
  const float* bih_w = (const float*)d_in[4];
  const float* bhh_w = (const float*)d_in[5];
  const float* Wih   = (const float*)d_in[6];
  const float* Whh   = (const float*)d_in[7];
  const float* bih   = (const float*)d_in[8];
  const float* bhh   = (const float*)d_in[9];
  const float* W_ss  = (const float*)d_in[10];
  const float* b_ss  = (const float*)d_in[11];
  const int* walks = (const int*)d_in[12];
  const int* idxs  = (const int*)d_in[13];
  float* out = (float*)d_out;
  float* ws = (float*)d_ws;

  (void)hipFuncSetAttribute((const void*)k_rum,
                            hipFuncAttributeMaxDynamicSharedMemorySize, LDS_TOTAL);

  k_zero<<<1, 64, 0, stream>>>(ws);
  k_prep<<<W_TOTAL / 256, 256, 0, stream>>>(Whh_w, Whh, Wih, ws);

  const int grid = NSEQ / MA;               // 2500, exact
  k_rum<<<grid, TA, LDS_TOTAL, stream>>>(hfeat, y0, Wih_w, bih_w, bhh_w,
                                         bih, bhh, W_ss, b_ss,
                                         walks, idxs, out, ws);

  k_final<<<1, 64, 0, stream>>>(ws, out);
}